// Round 5
// baseline (2572.307 us; speedup 1.0000x reference)
//
#include <hip/hip_runtime.h>

// AttentionHead: B=16384, W=10, D=1024, K=V=64
// out[b,i,:] = softmax_j( min(k_i . q_j, tri) ) @ v      (convention A per source:
//   scores = einsum('bik,bjk->bij', k, q), row = key index; tri = +1e5 for j<=i,
//   -1e5 strict upper; elementwise MINIMUM then softmax over j)
//
// ROUND-5 FIX: output dtype is FLOAT32 (reference is pure f32 -> d_out is float*).
// Rounds 0-4 wrote bf16 into an f32 buffer; the scrambled half-filled read
// explains the bit-identical absmax=158.5 across four independent builds.
//
// Numerics: f64 GEMM accumulation + f64 scores/softmax/PV (bisect-grade
// correctness baseline; MFMA fast path returns once this passes).

#define D 1024
#define BM 80            // 8 batches of 10 rows per block
#define XSTR 68          // x-stage row stride (floats)
#define KSTR 200         // kqv row stride (floats): [0:64]=k [64:128]=q [128:192]=v

typedef __attribute__((ext_vector_type(4))) float f32x4;

__global__ __launch_bounds__(512, 1) void fused_attn_a(
        const float* __restrict__ x,
        const float* __restrict__ w1,   // wk: row-side projection (scores row = key)
        const float* __restrict__ w2,   // wq: col-side projection (scores col = query)
        const float* __restrict__ wv,
        float* __restrict__ out) {

    __shared__ char smem[71040];
    float*  xs  = (float*)smem;              // GEMM phase: [80][XSTR] = 21760 B
    float*  kqv = (float*)smem;              // epilogue:   [80][KSTR] = 64000 B
    double* scd = (double*)(smem + 64000);   // 8 waves x 110 doubles = 7040 B

    const int tid = threadIdx.x;
    const int wid = tid >> 6;                // wave 0..7 == batch-in-block
    const int ln  = tid & 63;
    const int m0  = blockIdx.x * BM;

    // wave wid owns rows wid*10 .. wid*10+9 (its own attention batch),
    // lane ln owns output column ln of each of the 3 projections.
    double acc[10][3] = {};

    for (int ch = 0; ch < 16; ++ch) {
        __syncthreads();
        // stage x[80][64] f32 chunk (1280 float4s over 512 threads)
        #pragma unroll
        for (int it = 0; it < 3; ++it) {
            int p = tid + it * 512;
            if (p < 1280) {
                int row = p >> 4;
                int c4  = (p & 15) << 2;
                const float4 xvv = *reinterpret_cast<const float4*>(
                    x + (size_t)(m0 + row) * D + ch * 64 + c4);
                *reinterpret_cast<float4*>(xs + row * XSTR + c4) = xvv;
            }
        }
        __syncthreads();

        for (int d4 = 0; d4 < 16; ++d4) {
            double wr[4][3];
            #pragma unroll
            for (int e = 0; e < 4; ++e) {
                size_t off = (size_t)(ch * 64 + d4 * 4 + e) * 64 + ln;
                wr[e][0] = (double)w1[off];
                wr[e][1] = (double)w2[off];
                wr[e][2] = (double)wv[off];
            }
            #pragma unroll
            for (int rr = 0; rr < 10; ++rr) {
                const f32x4 xv = *reinterpret_cast<const f32x4*>(
                    xs + (wid * 10 + rr) * XSTR + d4 * 4);
                #pragma unroll
                for (int e = 0; e < 4; ++e) {
                    const double xe = (double)xv[e];
                    acc[rr][0] += xe * wr[e][0];
                    acc[rr][1] += xe * wr[e][1];
                    acc[rr][2] += xe * wr[e][2];
                }
            }
        }
    }

    // dump projections (f64 accum -> f32 storage; ~1e-3 logit rounding, far
    // below decision-relevant scales)
    __syncthreads();
    #pragma unroll
    for (int rr = 0; rr < 10; ++rr) {
        #pragma unroll
        for (int g = 0; g < 3; ++g)
            kqv[(wid * 10 + rr) * KSTR + g * 64 + ln] = (float)acc[rr][g];
    }
    __syncthreads();

    // ---- per-wave attention on its own batch, f64 ----
    const int r0 = wid * 10;
    double* sc = scd + wid * 110;

    #pragma unroll
    for (int it = 0; it < 2; ++it) {
        int p = it * 64 + ln;
        if (p < 100) {
            int i = p / 10;          // key index (row)
            int j = p - i * 10;      // query index (col)
            double s = 0.0;
            #pragma unroll 8
            for (int c = 0; c < 64; ++c)
                s += (double)kqv[(r0 + i) * KSTR + c] *
                     (double)kqv[(r0 + j) * KSTR + 64 + c];
            double lim = (j <= i) ? 1e5 : -1e5;
            sc[i * 11 + j] = fmin(s, lim);
        }
    }
    __syncthreads();

    if (ln < 10) {
        int i = ln;
        double vals[10];
        double mx = -1e300;
        #pragma unroll
        for (int j = 0; j < 10; ++j) { vals[j] = sc[i * 11 + j]; mx = fmax(mx, vals[j]); }
        double sum = 0.0;
        #pragma unroll
        for (int j = 0; j < 10; ++j) { vals[j] = exp(vals[j] - mx); sum += vals[j]; }
        double inv = 1.0 / sum;
        #pragma unroll
        for (int j = 0; j < 10; ++j) sc[i * 11 + j] = vals[j] * inv;
    }
    __syncthreads();

    size_t ob = (size_t)(blockIdx.x * 8 + wid) * 640;
    #pragma unroll
    for (int i = 0; i < 10; ++i) {
        double o = 0.0;
        #pragma unroll
        for (int j = 0; j < 10; ++j)
            o += sc[i * 11 + j] * (double)kqv[(r0 + j) * KSTR + 128 + ln];
        out[ob + (size_t)i * 64 + ln] = (float)o;
    }
}

extern "C" void kernel_launch(void* const* d_in, const int* in_sizes, int n_in,
                              void* d_out, int out_size, void* d_ws, size_t ws_size,
                              hipStream_t stream) {
    const float* x  = (const float*)d_in[0];
    const float* wk = (const float*)d_in[1];
    const float* wq = (const float*)d_in[2];
    const float* wv = (const float*)d_in[3];
    float* outp = (float*)d_out;     // FLOAT32 output (reference output dtype)

    // Convention A (per source): scores[i,j] = k_i . q_j -> w1 = wk, w2 = wq
    fused_attn_a<<<2048, 512, 0, stream>>>(x, wk, wq, wv, outp);
}

// Round 7
// 411.100 us; speedup vs baseline: 6.2571x; 6.2571x over previous
//
#include <hip/hip_runtime.h>

// AttentionHead: B=16384, W=10, D=1024, K=V=64
// out[b,i,:] = softmax_j( min(k_i . q_j, tri) ) @ v    (scores row = key index)
//
// GEMM front-end: 6-term split-bf16 MFMA (x,w each split into 3 bf16 pieces;
// keep products hh,hm,mh,hl,mm,lh >= 2^-16 significance) -> per-element
// projection error ~1.5e-5, below the np-f32 reference's own ~3.5e-5 noise.
// Attention epilogue: f64 (identical math to the round-5 PASSING build).
// Output: FLOAT32.

#define D 1024
#define BM 80            // 8 batches of 10 rows per block
#define KCHUNKS 16       // 1024 / 64
#define ASTR 72          // staged row stride in shorts (64 data + 8 pad)
#define KSTR 200         // kqv row stride in floats (192 data + 8 pad)

typedef __attribute__((ext_vector_type(8))) short bf16x8;
typedef __attribute__((ext_vector_type(4))) float f32x4;
typedef __attribute__((ext_vector_type(4))) unsigned short u16x4;

static __device__ __forceinline__ unsigned short f2bf_rtne(float f) {
    unsigned int u = __builtin_bit_cast(unsigned int, f);
    u += 0x7fffu + ((u >> 16) & 1u);
    return (unsigned short)(u >> 16);
}
static __device__ __forceinline__ float bf2f(unsigned short h) {
    unsigned int u = ((unsigned int)h) << 16;
    return __builtin_bit_cast(float, u);
}

// --- kernel0: split wk|wq|wv into transposed bf16 3-piece Wt[n][k]
__global__ __launch_bounds__(256) void prep_w(const float* __restrict__ wk,
                                              const float* __restrict__ wq,
                                              const float* __restrict__ wv,
                                              unsigned short* __restrict__ wth,
                                              unsigned short* __restrict__ wtm,
                                              unsigned short* __restrict__ wtl) {
    int idx = blockIdx.x * 256 + threadIdx.x;   // idx = n*1024 + kk, n in [0,192)
    int n  = idx >> 10;
    int kk = idx & 1023;
    const float* src = (n < 64) ? wk : (n < 128) ? wq : wv;
    float w = src[kk * 64 + (n & 63)];
    unsigned short h = f2bf_rtne(w);
    float r1 = w - bf2f(h);                     // exact
    unsigned short m = f2bf_rtne(r1);
    float r2 = r1 - bf2f(m);                    // exact
    wth[idx] = h;
    wtm[idx] = m;
    wtl[idx] = f2bf_rtne(r2);                   // residual <= 2^-25 |w|
}

// --- kernel1: fused 6-term projection GEMM + f64 attention
__global__ __launch_bounds__(256, 2) void fused_attn(
        const float* __restrict__ x,
        const unsigned short* __restrict__ wth,
        const unsigned short* __restrict__ wtm,
        const unsigned short* __restrict__ wtl,
        float* __restrict__ out) {

    __shared__ char smem[67520];
    unsigned short* AhS = (unsigned short*)smem;            // [80][ASTR] = 11520 B
    unsigned short* AmS = (unsigned short*)(smem + 11520);
    unsigned short* AlS = (unsigned short*)(smem + 23040);
    float*  kqv = (float*)smem;                             // [80][KSTR] = 64000 B
    double* scd = (double*)(smem + 64000);                  // 4 waves x 110 f64

    const int tid  = threadIdx.x;
    const int wave = tid >> 6;
    const int lane = tid & 63;
    const int m0   = blockIdx.x * BM;
    const int nbase = wave * 48;          // 3 n-tiles of 16 per wave (192 total)
    const int arow  = lane & 15;
    const int apart = lane >> 4;          // 0..3

    // ---------- layout probe: discover acc (lane,reg) -> (row, col) ----------
    for (int i = tid; i < 80 * ASTR; i += 256) AhS[i] = 0;
    __syncthreads();
    if (tid < 80) AhS[tid * ASTR] = f2bf_rtne((float)(tid + 1));  // A[m][0] = m+1
    __syncthreads();
    bf16x8 aprobe = *reinterpret_cast<const bf16x8*>((char*)AhS + arow * (ASTR * 2) + apart * 16);
    bf16x8 bone = {}, aone = {}, bcol = {};
    if (apart == 0) {
        bone[0] = (short)0x3F80;                              // B[0][n] = 1
        aone[0] = (short)0x3F80;                              // A[m][0] = 1
        bcol[0] = (short)f2bf_rtne((float)(arow + 1));        // B[0][n] = n+1
    }
    f32x4 z = {0.f, 0.f, 0.f, 0.f};
    f32x4 d1 = __builtin_amdgcn_mfma_f32_16x16x32_bf16(aprobe, bone, z, 0, 0, 0); // row+1
    f32x4 d2 = __builtin_amdgcn_mfma_f32_16x16x32_bf16(aone,  bcol, z, 0, 0, 0);  // col+1
    int R[4], Cc[4];
    #pragma unroll
    for (int r = 0; r < 4; ++r) {
        R[r]  = (int)(d1[r] + 0.5f) - 1;
        Cc[r] = (int)(d2[r] + 0.5f) - 1;
    }

    // ---------- GEMM: kqv[80][192] = x_chunk @ [wk|wq|wv], 6-term split ----------
    f32x4 acc[5][3] = {};                 // 5 m-tiles x 3 n-tiles

    for (int ch = 0; ch < KCHUNKS; ++ch) {
        __syncthreads();
        // stage 80 rows x 64 k of x, fp32 -> 3-piece bf16 (truncation cascade)
        #pragma unroll
        for (int it = 0; it < 5; ++it) {
            int p   = tid + it * 256;        // 0..1279
            int row = p >> 4;                // 0..79
            int c4  = (p & 15) << 2;         // col 0,4,...,60
            const float4 xv = *reinterpret_cast<const float4*>(
                x + (size_t)(m0 + row) * D + ch * 64 + c4);
            u16x4 hh, mm, ll;
            #pragma unroll
            for (int e = 0; e < 4; ++e) {
                float xe = (e == 0) ? xv.x : (e == 1) ? xv.y : (e == 2) ? xv.z : xv.w;
                unsigned short h = (unsigned short)(__builtin_bit_cast(unsigned int, xe) >> 16);
                float r1 = xe - bf2f(h);
                unsigned short mq = (unsigned short)(__builtin_bit_cast(unsigned int, r1) >> 16);
                float r2 = r1 - bf2f(mq);
                unsigned short l = (unsigned short)(__builtin_bit_cast(unsigned int, r2) >> 16);
                hh[e] = h; mm[e] = mq; ll[e] = l;
            }
            *reinterpret_cast<u16x4*>(AhS + row * ASTR + c4) = hh;
            *reinterpret_cast<u16x4*>(AmS + row * ASTR + c4) = mm;
            *reinterpret_cast<u16x4*>(AlS + row * ASTR + c4) = ll;
        }
        __syncthreads();

        #pragma unroll
        for (int ks = 0; ks < 2; ++ks) {
            // B fragments from L2 (same W for all blocks), 16B/lane contiguous
            bf16x8 wfh[3], wfm[3], wfl[3];
            #pragma unroll
            for (int nt = 0; nt < 3; ++nt) {
                int n = nbase + nt * 16 + arow;
                size_t off = (size_t)n * D + ch * 64 + ks * 32 + apart * 8;
                wfh[nt] = *reinterpret_cast<const bf16x8*>(wth + off);
                wfm[nt] = *reinterpret_cast<const bf16x8*>(wtm + off);
                wfl[nt] = *reinterpret_cast<const bf16x8*>(wtl + off);
            }
            #pragma unroll
            for (int mt = 0; mt < 5; ++mt) {
                int ab = (mt * 16 + arow) * (ASTR * 2) + (ks * 4 + apart) * 16;
                bf16x8 ah = *reinterpret_cast<const bf16x8*>((char*)AhS + ab);
                bf16x8 am = *reinterpret_cast<const bf16x8*>((char*)AmS + ab);
                bf16x8 al = *reinterpret_cast<const bf16x8*>((char*)AlS + ab);
                #pragma unroll
                for (int nt = 0; nt < 3; ++nt) {
                    // 6 terms: hh, hm, mh, hl, mm, lh  (drop 2^-24 and below)
                    acc[mt][nt] = __builtin_amdgcn_mfma_f32_16x16x32_bf16(ah, wfh[nt], acc[mt][nt], 0, 0, 0);
                    acc[mt][nt] = __builtin_amdgcn_mfma_f32_16x16x32_bf16(ah, wfm[nt], acc[mt][nt], 0, 0, 0);
                    acc[mt][nt] = __builtin_amdgcn_mfma_f32_16x16x32_bf16(am, wfh[nt], acc[mt][nt], 0, 0, 0);
                    acc[mt][nt] = __builtin_amdgcn_mfma_f32_16x16x32_bf16(ah, wfl[nt], acc[mt][nt], 0, 0, 0);
                    acc[mt][nt] = __builtin_amdgcn_mfma_f32_16x16x32_bf16(am, wfm[nt], acc[mt][nt], 0, 0, 0);
                    acc[mt][nt] = __builtin_amdgcn_mfma_f32_16x16x32_bf16(al, wfh[nt], acc[mt][nt], 0, 0, 0);
                }
            }
        }
    }

    // ---------- epilogue: dump all 80 rows, then f64 attention (round-5 math) ----------
    __syncthreads();
    #pragma unroll
    for (int mt = 0; mt < 5; ++mt) {
        #pragma unroll
        for (int r = 0; r < 4; ++r) {
            int row = mt * 16 + R[r];
            #pragma unroll
            for (int nt = 0; nt < 3; ++nt)
                kqv[row * KSTR + nbase + nt * 16 + Cc[r]] = acc[mt][nt][r];
        }
    }
    __syncthreads();

    double* sc = scd + wave * 110;
    for (int bb = 0; bb < 2; ++bb) {
        const int bloc = wave * 2 + bb;       // 0..7 within block
        const int r0   = bloc * 10;
        // scores: s[i][j] = k_i . q_j (f64), masked
        #pragma unroll
        for (int it = 0; it < 2; ++it) {
            int p = it * 64 + lane;
            if (p < 100) {
                int i = p / 10;
                int j = p - i * 10;
                double s = 0.0;
                #pragma unroll 8
                for (int c = 0; c < 64; ++c)
                    s += (double)kqv[(r0 + i) * KSTR + c] *
                         (double)kqv[(r0 + j) * KSTR + 64 + c];
                double lim = (j <= i) ? 1e5 : -1e5;
                sc[i * 11 + j] = fmin(s, lim);
            }
        }
        __syncthreads();
        // softmax over j (f64)
        if (lane < 10) {
            int i = lane;
            double vals[10];
            double mx = -1e300;
            #pragma unroll
            for (int j = 0; j < 10; ++j) { vals[j] = sc[i * 11 + j]; mx = fmax(mx, vals[j]); }
            double sum = 0.0;
            #pragma unroll
            for (int j = 0; j < 10; ++j) { vals[j] = exp(vals[j] - mx); sum += vals[j]; }
            double inv = 1.0 / sum;
            #pragma unroll
            for (int j = 0; j < 10; ++j) sc[i * 11 + j] = vals[j] * inv;
        }
        __syncthreads();
        // PV (f64) + f32 store: lane = output column
        size_t ob = (size_t)(blockIdx.x * 8 + bloc) * 640;
        #pragma unroll
        for (int i = 0; i < 10; ++i) {
            double o = 0.0;
            #pragma unroll
            for (int j = 0; j < 10; ++j)
                o += sc[i * 11 + j] * (double)kqv[(r0 + j) * KSTR + 128 + lane];
            out[ob + (size_t)i * 64 + lane] = (float)o;
        }
        __syncthreads();
    }
}

extern "C" void kernel_launch(void* const* d_in, const int* in_sizes, int n_in,
                              void* d_out, int out_size, void* d_ws, size_t ws_size,
                              hipStream_t stream) {
    const float* x  = (const float*)d_in[0];
    const float* wk = (const float*)d_in[1];
    const float* wq = (const float*)d_in[2];
    const float* wv = (const float*)d_in[3];
    unsigned short* wth = (unsigned short*)d_ws;          // 3 x 192*1024 bf16
    unsigned short* wtm = wth + 192 * 1024;
    unsigned short* wtl = wtm + 192 * 1024;
    float* outp = (float*)d_out;                          // FLOAT32 output

    prep_w<<<768, 256, 0, stream>>>(wk, wq, wv, wth, wtm, wtl);
    fused_attn<<<2048, 256, 0, stream>>>(x, wth, wtm, wtl, outp);
}